// Round 13
// baseline (1274.246 us; speedup 1.0000x reference)
//
#include <hip/hip_runtime.h>

typedef unsigned int uint;
typedef unsigned short ushort;
typedef unsigned long long u64;
typedef __attribute__((ext_vector_type(2))) float f32x2;

#define N_PTS 4096
#define B_SZ 16
#define M_PTS 1024
#define K_SMP 32
#define NROWS (B_SZ*M_PTS*K_SMP)   /* 524288 */
#define INV_CNT (1.0f/524288.0f)   /* exact: 2^-19 */

// ---------- helpers ----------
__device__ __forceinline__ float sqdist3(float ax,float ay,float az,float bx,float by,float bz){
  // exact-match of numpy/XLA f32: separate sub/mul/add, no FMA contraction
  float dx=__fsub_rn(ax,bx), dy=__fsub_rn(ay,by), dz=__fsub_rn(az,bz);
  return __fadd_rn(__fadd_rn(__fmul_rn(dx,dx),__fmul_rn(dy,dy)),__fmul_rn(dz,dz));
}
__device__ __forceinline__ ushort f2bf(float x){
  uint u = __float_as_uint(x);
  u = (u + 0x7fffu + ((u>>16)&1u)) >> 16;   // RNE
  return (ushort)u;
}
__device__ __forceinline__ float bf2f(uint u){ return __uint_as_float(u<<16); }

// packed f32 pair ops (VOP3P, IEEE RN per element -> bit-exact vs scalar;
// a + (-b) is exactly a - b)
__device__ __forceinline__ f32x2 pk_add(f32x2 a, f32x2 b){
  f32x2 d; asm("v_pk_add_f32 %0, %1, %2" : "=v"(d) : "v"(a), "v"(b)); return d;
}
__device__ __forceinline__ f32x2 pk_mul(f32x2 a, f32x2 b){
  f32x2 d; asm("v_pk_mul_f32 %0, %1, %2" : "=v"(d) : "v"(a), "v"(b)); return d;
}

template<int CTRL>
__device__ __forceinline__ uint dppu(uint v){
  return (uint)__builtin_amdgcn_update_dpp((int)v, (int)v, CTRL, 0xf, 0xf, false);
}
template<int CTRL>
__device__ __forceinline__ float dppmaxf(float v){
  float o = __uint_as_float(dppu<CTRL>(__float_as_uint(v)));
  return fmaxf(v, o);
}
// scan merge: incoming lane holds STRICTLY LOWER point indices, so exact
// lowest-index-on-tie == take incoming iff in.val >= own.val (3 ops)
template<int CTRL>
__device__ __forceinline__ void dppscan(float& v, uint& i){
  float ov = __uint_as_float(dppu<CTRL>(__float_as_uint(v)));
  uint  oi = dppu<CTRL>(i);
  bool tk = (ov >= v);
  v = tk ? ov : v;
  i = tk ? oi : i;
}

// ---------- 1. FPS: 1024 thr (4 waves/SIMD), 4 contiguous pts, pk dist, ballot ----------
// r12 post-mortem: with 2 waves/SIMD, issue (~1050cyc) and barrier chain (~450)
// ADD. 4 waves/SIMD + pk-dist cuts per-SIMD issue to ~520cyc. Coords loaded
// from GLOBAL (r3 lesson: LDS-sourced register arrays get rematerialized).
__global__ __launch_bounds__(1024) void fps_kernel(const float* __restrict__ xyz,
                                                   float* __restrict__ out_newxyz){
  const int b = blockIdx.x;
  const int t = threadIdx.x;
  __shared__ float4 sxyz[N_PTS];             // 64 KB: winner-coord fetch ONLY
  __shared__ __align__(8) uint2 xch[2][16];  // per-wave {max_bits, argidx}, parity dbuf
  const float* src = xyz + (size_t)b*N_PTS*3;
  // conflict-free strided sxyz fill (separate from register ownership)
  for (int i = t; i < N_PTS; i += 1024)
    sxyz[i] = make_float4(src[3*i], src[3*i+1], src[3*i+2], 0.f);
  // 4 CONTIGUOUS points [4t, 4t+4) in registers via 3 float4 global loads
  const int p0 = t*4;
  f32x2 px01, py01, pz01, px23, py23, pz23, d01, d23;
  {
    const float4* s4 = (const float4*)(src + 3*p0);   // 48B-aligned
    float4 v0 = s4[0], v1 = s4[1], v2 = s4[2];
    px01 = f32x2{v0.x, v0.w}; py01 = f32x2{v0.y, v1.x}; pz01 = f32x2{v0.z, v1.y};
    px23 = f32x2{v1.z, v2.y}; py23 = f32x2{v1.w, v2.z}; pz23 = f32x2{v2.x, v2.w};
    d01 = f32x2{1e10f, 1e10f}; d23 = f32x2{1e10f, 1e10f};
  }
  __syncthreads();
  float cx, cy, cz;
  { float4 c0 = sxyz[0]; cx=c0.x; cy=c0.y; cz=c0.z; }
  const int w = t >> 6, lane = t & 63;
  float* outx = out_newxyz + (size_t)b*M_PTS*3;
  for (int s = 0; s < M_PTS; ++s){
    if (t == 0){ outx[s*3+0]=cx; outx[s*3+1]=cy; outx[s*3+2]=cz; }
    // A: packed dist update: d = (dx*dx + dy*dy) + dz*dz  (ref op order, RN)
    const f32x2 ncx = f32x2{-cx,-cx}, ncy = f32x2{-cy,-cy}, ncz = f32x2{-cz,-cz};
    {
      f32x2 dx = pk_add(px01, ncx);
      f32x2 dy = pk_add(py01, ncy);
      f32x2 dz = pk_add(pz01, ncz);
      f32x2 d  = pk_add(pk_add(pk_mul(dx,dx), pk_mul(dy,dy)), pk_mul(dz,dz));
      d01.x = fminf(d01.x, d.x);
      d01.y = fminf(d01.y, d.y);
    }
    {
      f32x2 dx = pk_add(px23, ncx);
      f32x2 dy = pk_add(py23, ncy);
      f32x2 dz = pk_add(pz23, ncz);
      f32x2 d  = pk_add(pk_add(pk_mul(dx,dx), pk_mul(dy,dy)), pk_mul(dz,dz));
      d23.x = fminf(d23.x, d.x);
      d23.y = fminf(d23.y, d.y);
    }
    // local max of 4 + lowest matching slot (iterate high->low)
    float m4 = fmaxf(fmaxf(d01.x, d01.y), fmaxf(d23.x, d23.y));
    uint li = 3;
    if (d23.x == m4) li = 2;
    if (d01.y == m4) li = 1;
    if (d01.x == m4) li = 0;
    const uint gi = (uint)p0 + li;
    // B: wave scan-max (2 ops/stage) -> lane 63 = wave max
    float wm = m4;
    wm = dppmaxf<0x111>(wm);  // row_shr:1
    wm = dppmaxf<0x112>(wm);  // row_shr:2
    wm = dppmaxf<0x114>(wm);  // row_shr:4
    wm = dppmaxf<0x118>(wm);  // row_shr:8
    wm = dppmaxf<0x142>(wm);  // row_bcast:15
    wm = dppmaxf<0x143>(wm);  // row_bcast:31
    const float M = __uint_as_float((uint)__builtin_amdgcn_readlane((int)__float_as_uint(wm), 63));
    // ballot argmin: lowest lane with m4==M == lowest point index (contiguous)
    unsigned long long blt = __ballot(m4 == M);
    const int ll = __builtin_ctzll(blt);
    const uint widx = (uint)__builtin_amdgcn_readlane((int)gi, ll);
    // C: cross-wave merge over 16 wave winners (wave order = index order)
    const int par = s & 1;
    if (lane == 63) xch[par][w] = make_uint2(__float_as_uint(M), widx);
    __syncthreads();
    uint2 cw = xch[par][lane & 15];
    float cv = __uint_as_float(cw.x); uint ci = cw.y;
    dppscan<0x111>(cv, ci);
    dppscan<0x112>(cv, ci);
    dppscan<0x114>(cv, ci);
    dppscan<0x118>(cv, ci);       // lane 15 (each row) = global winner
    uint fi = (uint)__builtin_amdgcn_readlane((int)ci, 15);
    float4 cc = sxyz[fi];         // uniform broadcast read
    cx = cc.x; cy = cc.y; cz = cc.z;
  }
}

// ---------- 2. ball query (exact f32, first-32 in index order) ----------
__global__ __launch_bounds__(256) void ballq_kernel(const float* __restrict__ xyz,
                                                    const float* __restrict__ newxyz,
                                                    int* __restrict__ gidx){
  const int blk = blockIdx.x;
  const int b = blk >> 6;
  const int mbase = (blk & 63) * 16;
  __shared__ float sx[N_PTS], sy[N_PTS], sz[N_PTS];
  const float* src = xyz + (size_t)b*N_PTS*3;
  for (int i = threadIdx.x; i < N_PTS*3; i += 256){
    float v = src[i]; int p = i/3, j = i%3;
    (j==0?sx:(j==1?sy:sz))[p] = v;
  }
  __syncthreads();
  const int w = threadIdx.x >> 6, lane = threadIdx.x & 63;
  const float R2 = (float)(0.2*0.2);   // f32(f64 product) — matches reference cast
  for (int mm = w; mm < 16; mm += 4){
    const int m = mbase + mm;
    const float* c = newxyz + ((size_t)b*M_PTS + m)*3;
    float cx = c[0], cy = c[1], cz = c[2];
    int* gout = gidx + ((size_t)b*M_PTS + m)*K_SMP;
    int cnt = 0;
    for (int base = 0; base < N_PTS && cnt < K_SMP; base += 64){
      int p = base + lane;
      float d = sqdist3(sx[p],sy[p],sz[p],cx,cy,cz);
      bool in = (d <= R2);
      unsigned long long mask = __ballot(in);
      int prefix = __popcll(mask & ((1ull << lane) - 1ull));
      int slot = cnt + prefix;
      if (in && slot < K_SMP) gout[slot] = p;
      cnt += __popcll(mask);
    }
    if (cnt < K_SMP){
      int slot = cnt + lane;
      if (slot < K_SMP) gout[slot] = 0;
    }
  }
}

// ---------- conv0: LDS-tiled GEMM, 128 rows x 64 outs, K=67, acc 8x4 ----------
__global__ __launch_bounds__(256, 2) void conv0_kernel(const float* __restrict__ xyz,
                                                       const float* __restrict__ points,
                                                       const float* __restrict__ newxyz,
                                                       const int* __restrict__ gidx,
                                                       const float* __restrict__ W0,
                                                       const float* __restrict__ b0,
                                                       ushort* __restrict__ x1){
  __shared__ float A [67][132];    // [k][row] 35.4 KB
  __shared__ float Bw[67][68];     // [k][out] 18.2 KB
  __shared__ float sb[64];
  const int tid = threadIdx.x;
  if (tid < 64) sb[tid] = b0[tid];
  for (int idx = tid; idx < 64*67; idx += 256){
    int o = idx / 67, k = idx - o*67;
    Bw[k][o] = W0[idx];
  }
  const size_t rbase = (size_t)blockIdx.x * 128;
  {
    const int r  = tid & 127;
    const int hf = tid >> 7;           // half of the 64 points-channels
    const int R = (int)rbase + r;
    const int b_ = R >> 15, m_ = (R >> 5) & 1023;
    const int g_ = gidx[R];
    const float4* p4 = (const float4*)(points + (((size_t)(b_<<12) + g_) << 6) + hf*32);
#pragma unroll
    for (int j=0;j<8;j++){
      float4 v = p4[j];
      int c = 3 + hf*32 + j*4;
      A[c+0][r]=v.x; A[c+1][r]=v.y; A[c+2][r]=v.z; A[c+3][r]=v.w;
    }
    if (hf == 0){
      const float* pc = newxyz + ((size_t)(b_<<10) + m_)*3;
      const float* pp = xyz    + ((size_t)(b_<<12) + g_)*3;
      A[0][r] = pp[0]-pc[0];
      A[1][r] = pp[1]-pc[1];
      A[2][r] = pp[2]-pc[2];
    }
  }
  __syncthreads();
  const int tr = tid >> 4, tc = tid & 15;   // 8 rows x 4 cols per thread
  float acc[8][4];
#pragma unroll
  for (int i=0;i<8;i++)
#pragma unroll
    for (int j=0;j<4;j++) acc[i][j] = sb[tc*4+j];
#pragma unroll 4
  for (int k=0;k<67;k++){
    float4 a0 = *(const float4*)&A [k][tr*8];
    float4 a1 = *(const float4*)&A [k][tr*8+4];
    float4 w  = *(const float4*)&Bw[k][tc*4];
    float av[8] = {a0.x,a0.y,a0.z,a0.w,a1.x,a1.y,a1.z,a1.w};
#pragma unroll
    for (int i=0;i<8;i++){
      acc[i][0]=fmaf(av[i],w.x,acc[i][0]);
      acc[i][1]=fmaf(av[i],w.y,acc[i][1]);
      acc[i][2]=fmaf(av[i],w.z,acc[i][2]);
      acc[i][3]=fmaf(av[i],w.w,acc[i][3]);
    }
  }
#pragma unroll
  for (int i=0;i<8;i++){
    uint2 v;
    v.x = (uint)f2bf(acc[i][0]) | ((uint)f2bf(acc[i][1])<<16);
    v.y = (uint)f2bf(acc[i][2]) | ((uint)f2bf(acc[i][3])<<16);
    *(uint2*)(x1 + ((rbase + tr*8 + i) << 6) + tc*4) = v;
  }
}

// ---------- convg64 (conv1): BN+ReLU on read, 128x64 tile, K=64, acc 8x4 ----------
__global__ __launch_bounds__(256, 2) void convg64_kernel(const ushort* __restrict__ xin,
                                                         const float* __restrict__ Sv,
                                                         const float* __restrict__ SSv,
                                                         const float* __restrict__ gg,
                                                         const float* __restrict__ be,
                                                         const float* __restrict__ W,
                                                         const float* __restrict__ bias,
                                                         ushort* __restrict__ xout){
  __shared__ float A [64][132];    // [k][row] 33.8 KB
  __shared__ float Bw[64][68];     // [k][out] 17.4 KB
  __shared__ float sc[64], sh[64], sb[64];
  const int tid = threadIdx.x;
  if (tid < 64){
    int c = tid;
    float mean = Sv[c]*INV_CNT;
    float var  = fmaf(-mean, mean, SSv[c]*INV_CNT);
    float is   = rsqrtf(var + 1e-5f);
    float scv  = gg[c]*is;
    sc[c] = scv; sh[c] = fmaf(-mean, scv, be[c]);
    sb[c] = bias[c];
  }
  {
    const int o  = tid & 63;
    const int kq = tid >> 6;          // 0..3, 16 k each
    const float* wrow = W + (size_t)o*64 + kq*16;
#pragma unroll
    for (int q=0;q<4;q++){
      float4 wv = *(const float4*)(wrow + q*4);
      int k = kq*16 + q*4;
      Bw[k+0][o]=wv.x; Bw[k+1][o]=wv.y; Bw[k+2][o]=wv.z; Bw[k+3][o]=wv.w;
    }
  }
  __syncthreads();                    // sc/sh ready for A fill
  const size_t rbase = (size_t)blockIdx.x * 128;
  {
    const int r  = tid & 127;
    const int kh = tid >> 7;          // which 32-k half
    const uint4* src = (const uint4*)(xin + ((rbase + r) << 6) + kh*32);
#pragma unroll
    for (int g=0; g<4; g++){
      uint4 v = src[g];
      uint d[4] = {v.x,v.y,v.z,v.w};
#pragma unroll
      for (int q=0;q<4;q++){
        int k = kh*32 + g*8 + 2*q;
        float a0 = bf2f(d[q] & 0xffffu), a1 = bf2f(d[q] >> 16);
        A[k+0][r] = fmaxf(fmaf(a0, sc[k+0], sh[k+0]), 0.f);
        A[k+1][r] = fmaxf(fmaf(a1, sc[k+1], sh[k+1]), 0.f);
      }
    }
  }
  __syncthreads();
  const int tr = tid >> 4, tc = tid & 15;
  float acc[8][4];
#pragma unroll
  for (int i=0;i<8;i++)
#pragma unroll
    for (int j=0;j<4;j++) acc[i][j] = sb[tc*4+j];
#pragma unroll 4
  for (int k=0;k<64;k++){
    float4 a0 = *(const float4*)&A [k][tr*8];
    float4 a1 = *(const float4*)&A [k][tr*8+4];
    float4 w  = *(const float4*)&Bw[k][tc*4];
    float av[8] = {a0.x,a0.y,a0.z,a0.w,a1.x,a1.y,a1.z,a1.w};
#pragma unroll
    for (int i=0;i<8;i++){
      acc[i][0]=fmaf(av[i],w.x,acc[i][0]);
      acc[i][1]=fmaf(av[i],w.y,acc[i][1]);
      acc[i][2]=fmaf(av[i],w.z,acc[i][2]);
      acc[i][3]=fmaf(av[i],w.w,acc[i][3]);
    }
  }
#pragma unroll
  for (int i=0;i<8;i++){
    uint2 v;
    v.x = (uint)f2bf(acc[i][0]) | ((uint)f2bf(acc[i][1])<<16);
    v.y = (uint)f2bf(acc[i][2]) | ((uint)f2bf(acc[i][3])<<16);
    *(uint2*)(xout + ((rbase + tr*8 + i) << 6) + tc*4) = v;
  }
}

// ---------- convg128 (conv2): BN+ReLU on read, 128x128 tile, K=64, acc 8x8 ----------
__global__ __launch_bounds__(256, 2) void convg128_kernel(const ushort* __restrict__ xin,
                                                          const float* __restrict__ Sv,
                                                          const float* __restrict__ SSv,
                                                          const float* __restrict__ gg,
                                                          const float* __restrict__ be,
                                                          const float* __restrict__ W,
                                                          const float* __restrict__ bias,
                                                          ushort* __restrict__ xout){
  __shared__ float A [64][132];    // [k][row] 33.8 KB
  __shared__ float Bw[64][132];    // [k][out] 33.8 KB (128 used)
  __shared__ float sc[64], sh[64], sb[128];
  const int tid = threadIdx.x;
  if (tid < 64){
    int c = tid;
    float mean = Sv[c]*INV_CNT;
    float var  = fmaf(-mean, mean, SSv[c]*INV_CNT);
    float is   = rsqrtf(var + 1e-5f);
    float scv  = gg[c]*is;
    sc[c] = scv; sh[c] = fmaf(-mean, scv, be[c]);
  }
  if (tid < 128) sb[tid] = bias[tid];
  {
    const int o  = tid & 127;
    const int kh = tid >> 7;          // 0/1, 32 k each
    const float* wrow = W + (size_t)o*64 + kh*32;
#pragma unroll
    for (int q=0;q<8;q++){
      float4 wv = *(const float4*)(wrow + q*4);
      int k = kh*32 + q*4;
      Bw[k+0][o]=wv.x; Bw[k+1][o]=wv.y; Bw[k+2][o]=wv.z; Bw[k+3][o]=wv.w;
    }
  }
  __syncthreads();                    // sc/sh ready for A fill
  const size_t rbase = (size_t)blockIdx.x * 128;
  {
    const int r  = tid & 127;
    const int kh = tid >> 7;
    const uint4* src = (const uint4*)(xin + ((rbase + r) << 6) + kh*32);
#pragma unroll
    for (int g=0; g<4; g++){
      uint4 v = src[g];
      uint d[4] = {v.x,v.y,v.z,v.w};
#pragma unroll
      for (int q=0;q<4;q++){
        int k = kh*32 + g*8 + 2*q;
        float a0 = bf2f(d[q] & 0xffffu), a1 = bf2f(d[q] >> 16);
        A[k+0][r] = fmaxf(fmaf(a0, sc[k+0], sh[k+0]), 0.f);
        A[k+1][r] = fmaxf(fmaf(a1, sc[k+1], sh[k+1]), 0.f);
      }
    }
  }
  __syncthreads();
  const int tr = tid >> 4, tc = tid & 15;   // 8 rows x 8 cols per thread
  float acc[8][8];
#pragma unroll
  for (int i=0;i<8;i++)
#pragma unroll
    for (int j=0;j<8;j++) acc[i][j] = sb[tc*8+j];
#pragma unroll 2
  for (int k=0;k<64;k++){
    float4 a0 = *(const float4*)&A [k][tr*8];
    float4 a1 = *(const float4*)&A [k][tr*8+4];
    float4 w0 = *(const float4*)&Bw[k][tc*8];
    float4 w1 = *(const float4*)&Bw[k][tc*8+4];
    float av[8] = {a0.x,a0.y,a0.z,a0.w,a1.x,a1.y,a1.z,a1.w};
    float wv[8] = {w0.x,w0.y,w0.z,w0.w,w1.x,w1.y,w1.z,w1.w};
#pragma unroll
    for (int i=0;i<8;i++)
#pragma unroll
      for (int j=0;j<8;j++)
        acc[i][j] = fmaf(av[i], wv[j], acc[i][j]);
  }
#pragma unroll
  for (int i=0;i<8;i++){
    uint4 v;
    v.x = (uint)f2bf(acc[i][0]) | ((uint)f2bf(acc[i][1])<<16);
    v.y = (uint)f2bf(acc[i][2]) | ((uint)f2bf(acc[i][3])<<16);
    v.z = (uint)f2bf(acc[i][4]) | ((uint)f2bf(acc[i][5])<<16);
    v.w = (uint)f2bf(acc[i][6]) | ((uint)f2bf(acc[i][7])<<16);
    *(uint4*)(xout + ((rbase + tr*8 + i) << 7) + tc*8) = v;
  }
}

// ---------- stats: per-channel sum & sumsq, vectorized 8 ch/thread ----------
template<int C>
__global__ __launch_bounds__(256) void stats_kernel(const ushort* __restrict__ x,
                                                    float* __restrict__ S,
                                                    float* __restrict__ SS){
  constexpr int GRP = C/8;
  constexpr int RL  = 256/GRP;
  const int cg = threadIdx.x % GRP;
  const int rl = threadIdx.x / GRP;
  const int rows_per_block = NROWS / 1024;   // grid = 1024
  const int r0 = blockIdx.x * rows_per_block;
  float s[8], ss[8];
#pragma unroll
  for (int j=0;j<8;j++){ s[j]=0.f; ss[j]=0.f; }
  for (int r = r0 + rl; r < r0 + rows_per_block; r += RL){
    uint4 v = *(const uint4*)(x + (size_t)r*C + cg*8);
    uint d[4] = {v.x, v.y, v.z, v.w};
#pragma unroll
    for (int q=0;q<4;q++){
      float a0 = bf2f(d[q] & 0xffffu), a1 = bf2f(d[q] >> 16);
      s[2*q]   += a0; ss[2*q]   = fmaf(a0, a0, ss[2*q]);
      s[2*q+1] += a1; ss[2*q+1] = fmaf(a1, a1, ss[2*q+1]);
    }
  }
  __shared__ float ls[256][8], lss[256][8];
#pragma unroll
  for (int j=0;j<8;j++){ ls[threadIdx.x][j]=s[j]; lss[threadIdx.x][j]=ss[j]; }
  __syncthreads();
  if (threadIdx.x < C){
    const int grp = threadIdx.x >> 3, j = threadIdx.x & 7;
    float a = 0.f, q2 = 0.f;
#pragma unroll
    for (int q = 0; q < RL; q++){ a += ls[q*GRP + grp][j]; q2 += lss[q*GRP + grp][j]; }
    atomicAdd(&S[threadIdx.x], a); atomicAdd(&SS[threadIdx.x], q2);
  }
}

// ---------- BN2+ReLU + maxpool over K ----------
__global__ __launch_bounds__(256) void maxpool_kernel(const ushort* __restrict__ x3,
                                                      const float* __restrict__ S2,
                                                      const float* __restrict__ SS2,
                                                      const float* __restrict__ g2,
                                                      const float* __restrict__ be2,
                                                      float* __restrict__ outp){
  const int lane = threadIdx.x & 63, wv = threadIdx.x >> 6;
  const int bm = blockIdx.x*4 + wv;           // 16384 (b,m) groups
  const int c0 = lane*2, c1 = c0+1;
  float mean0 = S2[c0]*INV_CNT;
  float var0  = fmaf(-mean0, mean0, SS2[c0]*INV_CNT);
  float s0 = g2[c0]*rsqrtf(var0+1e-5f);
  float h0 = fmaf(-mean0, s0, be2[c0]);
  float mean1 = S2[c1]*INV_CNT;
  float var1  = fmaf(-mean1, mean1, SS2[c1]*INV_CNT);
  float s1 = g2[c1]*rsqrtf(var1+1e-5f);
  float h1 = fmaf(-mean1, s1, be2[c1]);
  const uint* rb = (const uint*)(x3 + (size_t)bm*K_SMP*128);
  float mx0 = 0.f, mx1 = 0.f;                 // relu floor
#pragma unroll
  for (int k=0;k<K_SMP;k++){
    uint v = rb[k*64 + lane];
    float a0 = bf2f(v & 0xffffu), a1 = bf2f(v >> 16);
    mx0 = fmaxf(mx0, fmaxf(fmaf(a0, s0, h0), 0.f));
    mx1 = fmaxf(mx1, fmaxf(fmaf(a1, s1, h1), 0.f));
  }
  float2* o2 = (float2*)(outp + (size_t)bm*128);
  o2[lane] = make_float2(mx0, mx1);
}

// ---------- launch ----------
extern "C" void kernel_launch(void* const* d_in, const int* in_sizes, int n_in,
                              void* d_out, int out_size, void* d_ws, size_t ws_size,
                              hipStream_t stream){
  const float* xyz    = (const float*)d_in[0];
  const float* points = (const float*)d_in[1];
  const float* w0  = (const float*)d_in[2];
  const float* b0  = (const float*)d_in[3];
  const float* g0  = (const float*)d_in[4];
  const float* be0 = (const float*)d_in[5];
  const float* w1  = (const float*)d_in[6];
  const float* b1  = (const float*)d_in[7];
  const float* g1  = (const float*)d_in[8];
  const float* be1 = (const float*)d_in[9];
  const float* w2  = (const float*)d_in[10];
  const float* b2  = (const float*)d_in[11];
  const float* g2  = (const float*)d_in[12];
  const float* be2 = (const float*)d_in[13];

  float* out      = (float*)d_out;
  float* newxyz   = out;                        // [16,1024,3]
  float* outp     = out + (size_t)B_SZ*M_PTS*3; // [16,1024,128]

  char* ws = (char*)d_ws;
  int*   gidx  = (int*)ws;
  float* stats = (float*)(ws + (2u<<20));
  float* S0 = stats,      *SS0 = stats+64;
  float* S1 = stats+128,  *SS1 = stats+192;
  float* S2 = stats+256,  *SS2 = stats+384;
  ushort* x1 = (ushort*)(ws + (4u<<20));
  ushort* x3 = (ushort*)(ws + (4u<<20));
  ushort* x2 = (ushort*)(ws + (4u<<20) + 134217728u);

  hipMemsetAsync(stats, 0, 512*sizeof(float), stream);
  fps_kernel  <<<B_SZ, 1024, 0, stream>>>(xyz, newxyz);
  ballq_kernel<<<1024, 256, 0, stream>>>(xyz, newxyz, gidx);
  conv0_kernel<<<NROWS/128, 256, 0, stream>>>(xyz, points, newxyz, gidx, w0, b0, x1);
  stats_kernel<64><<<1024, 256, 0, stream>>>(x1, S0, SS0);
  convg64_kernel<<<NROWS/128, 256, 0, stream>>>(x1, S0, SS0, g0, be0, w1, b1, x2);
  stats_kernel<64><<<1024, 256, 0, stream>>>(x2, S1, SS1);
  convg128_kernel<<<NROWS/128, 256, 0, stream>>>(x2, S1, SS1, g1, be1, w2, b2, x3);
  stats_kernel<128><<<1024, 256, 0, stream>>>(x3, S2, SS2);
  maxpool_kernel<<<NROWS/128, 256, 0, stream>>>(x3, S2, SS2, g2, be2, outp);
}

// Round 14
// 1064.572 us; speedup vs baseline: 1.1970x; 1.1970x over previous
//
#include <hip/hip_runtime.h>

typedef unsigned int uint;
typedef unsigned short ushort;
typedef unsigned long long u64;

#define N_PTS 4096
#define B_SZ 16
#define M_PTS 1024
#define K_SMP 32
#define NROWS (B_SZ*M_PTS*K_SMP)   /* 524288 */
#define INV_CNT (1.0f/524288.0f)   /* exact: 2^-19 */

// ---------- helpers ----------
__device__ __forceinline__ float sqdist3(float ax,float ay,float az,float bx,float by,float bz){
  // exact-match of numpy/XLA f32: separate sub/mul/add, no FMA contraction
  float dx=__fsub_rn(ax,bx), dy=__fsub_rn(ay,by), dz=__fsub_rn(az,bz);
  return __fadd_rn(__fadd_rn(__fmul_rn(dx,dx),__fmul_rn(dy,dy)),__fmul_rn(dz,dz));
}
__device__ __forceinline__ ushort f2bf(float x){
  uint u = __float_as_uint(x);
  u = (u + 0x7fffu + ((u>>16)&1u)) >> 16;   // RNE
  return (ushort)u;
}
__device__ __forceinline__ float bf2f(uint u){ return __uint_as_float(u<<16); }

template<int CTRL>
__device__ __forceinline__ uint dppu(uint v){
  return (uint)__builtin_amdgcn_update_dpp((int)v, (int)v, CTRL, 0xf, 0xf, false);
}
template<int CTRL>
__device__ __forceinline__ float dppmaxf(float v){
  float o = __uint_as_float(dppu<CTRL>(__float_as_uint(v)));
  return fmaxf(v, o);
}
// scan merge: incoming lane holds STRICTLY LOWER point indices, so exact
// lowest-index-on-tie == take incoming iff in.val >= own.val (3 ops)
template<int CTRL>
__device__ __forceinline__ void dppscan(float& v, uint& i){
  float ov = __uint_as_float(dppu<CTRL>(__float_as_uint(v)));
  uint  oi = dppu<CTRL>(i);
  bool tk = (ov >= v);
  v = tk ? ov : v;
  i = tk ? oi : i;
}

// ---------- 1. FPS: value-only DPP max + ballot argmin (r12 winner, 639us) ----------
// Best of 10 structural variants (639-1092us band). 512 thr = 2 waves/SIMD;
// more waves (r13: 1024thr) makes the per-step barrier slower than the issue
// saving. Contiguous ownership makes ballot's lowest-LANE == lowest-INDEX.
__global__ __launch_bounds__(512, 2) void fps_kernel(const float* __restrict__ xyz,
                                                     float* __restrict__ out_newxyz){
  const int b = blockIdx.x;
  const int t = threadIdx.x;
  __shared__ float4 sxyz[N_PTS];            // 64 KB: winner-coord fetch ONLY
  __shared__ __align__(8) uint2 xch[2][8];  // per-wave {max_bits, argidx}, parity dbuf
  const float* src = xyz + (size_t)b*N_PTS*3;
  // conflict-free strided sxyz fill (separate from register ownership)
  for (int i = t; i < N_PTS; i += 512)
    sxyz[i] = make_float4(src[3*i], src[3*i+1], src[3*i+2], 0.f);
  // 8 CONTIGUOUS points [8t, 8t+8) in registers via 6 float4 loads (96B aligned)
  const int p0 = t*8;
  float px[8], py[8], pz[8], dist[8];
  {
    const float4* s4 = (const float4*)(src + 3*p0);
    float4 v[6];
#pragma unroll
    for (int q=0;q<6;q++) v[q] = s4[q];
    const float* f = (const float*)v;
#pragma unroll
    for (int i=0;i<8;i++){
      px[i]=f[3*i]; py[i]=f[3*i+1]; pz[i]=f[3*i+2];
      dist[i]=1e10f;
    }
  }
  __syncthreads();
  float cx, cy, cz;
  { float4 c0 = sxyz[0]; cx=c0.x; cy=c0.y; cz=c0.z; }
  const int w = t >> 6, lane = t & 63;
  float* outx = out_newxyz + (size_t)b*M_PTS*3;
  for (int s = 0; s < M_PTS; ++s){
    if (t == 0){ outx[s*3+0]=cx; outx[s*3+1]=cy; outx[s*3+2]=cz; }
    // A: dist update (exact reference op order)
#pragma unroll
    for (int i=0;i<8;i++){
      float d = sqdist3(px[i],py[i],pz[i],cx,cy,cz);
      dist[i] = fminf(dist[i], d);
    }
    // local max (value only)
    float m8 = fmaxf(fmaxf(fmaxf(dist[0],dist[1]), fmaxf(dist[2],dist[3])),
                     fmaxf(fmaxf(dist[4],dist[5]), fmaxf(dist[6],dist[7])));
    // lowest matching slot (iterate high->low; last write = lowest i)
    uint li = 7;
    if (dist[6] == m8) li = 6;
    if (dist[5] == m8) li = 5;
    if (dist[4] == m8) li = 4;
    if (dist[3] == m8) li = 3;
    if (dist[2] == m8) li = 2;
    if (dist[1] == m8) li = 1;
    if (dist[0] == m8) li = 0;
    const uint gi = (uint)p0 + li;
    // B: wave scan-max of m8 (2 ops/stage) -> lane 63 = wave max
    float wm = m8;
    wm = dppmaxf<0x111>(wm);  // row_shr:1
    wm = dppmaxf<0x112>(wm);  // row_shr:2
    wm = dppmaxf<0x114>(wm);  // row_shr:4
    wm = dppmaxf<0x118>(wm);  // row_shr:8
    wm = dppmaxf<0x142>(wm);  // row_bcast:15
    wm = dppmaxf<0x143>(wm);  // row_bcast:31
    const float M = __uint_as_float((uint)__builtin_amdgcn_readlane((int)__float_as_uint(wm), 63));
    // ballot argmin: lowest lane with m8==M == lowest point index (contiguous)
    unsigned long long blt = __ballot(m8 == M);
    const int ll = __builtin_ctzll(blt);
    const uint widx = (uint)__builtin_amdgcn_readlane((int)gi, ll);
    // C: cross-wave merge over 8 wave winners (wave order = index order)
    const int par = s & 1;
    if (lane == 63) xch[par][w] = make_uint2(__float_as_uint(M), widx);
    __syncthreads();
    uint2 cw = xch[par][lane & 7];
    float cv = __uint_as_float(cw.x); uint ci = cw.y;
    dppscan<0x111>(cv, ci);
    dppscan<0x112>(cv, ci);
    dppscan<0x114>(cv, ci);       // lane 7 (each row) = global winner
    uint fi = (uint)__builtin_amdgcn_readlane((int)ci, 7);
    float4 cc = sxyz[fi];         // uniform broadcast read
    cx = cc.x; cy = cc.y; cz = cc.z;
  }
}

// ---------- 2. ball query (exact f32, first-32 in index order) ----------
__global__ __launch_bounds__(256) void ballq_kernel(const float* __restrict__ xyz,
                                                    const float* __restrict__ newxyz,
                                                    int* __restrict__ gidx){
  const int blk = blockIdx.x;
  const int b = blk >> 6;
  const int mbase = (blk & 63) * 16;
  __shared__ float sx[N_PTS], sy[N_PTS], sz[N_PTS];
  const float* src = xyz + (size_t)b*N_PTS*3;
  for (int i = threadIdx.x; i < N_PTS*3; i += 256){
    float v = src[i]; int p = i/3, j = i%3;
    (j==0?sx:(j==1?sy:sz))[p] = v;
  }
  __syncthreads();
  const int w = threadIdx.x >> 6, lane = threadIdx.x & 63;
  const float R2 = (float)(0.2*0.2);   // f32(f64 product) — matches reference cast
  for (int mm = w; mm < 16; mm += 4){
    const int m = mbase + mm;
    const float* c = newxyz + ((size_t)b*M_PTS + m)*3;
    float cx = c[0], cy = c[1], cz = c[2];
    int* gout = gidx + ((size_t)b*M_PTS + m)*K_SMP;
    int cnt = 0;
    for (int base = 0; base < N_PTS && cnt < K_SMP; base += 64){
      int p = base + lane;
      float d = sqdist3(sx[p],sy[p],sz[p],cx,cy,cz);
      bool in = (d <= R2);
      unsigned long long mask = __ballot(in);
      int prefix = __popcll(mask & ((1ull << lane) - 1ull));
      int slot = cnt + prefix;
      if (in && slot < K_SMP) gout[slot] = p;
      cnt += __popcll(mask);
    }
    if (cnt < K_SMP){
      int slot = cnt + lane;
      if (slot < K_SMP) gout[slot] = 0;
    }
  }
}

// ---------- conv0: LDS-tiled GEMM, 128 rows x 64 outs, K=67, acc 8x4 ----------
__global__ __launch_bounds__(256, 2) void conv0_kernel(const float* __restrict__ xyz,
                                                       const float* __restrict__ points,
                                                       const float* __restrict__ newxyz,
                                                       const int* __restrict__ gidx,
                                                       const float* __restrict__ W0,
                                                       const float* __restrict__ b0,
                                                       ushort* __restrict__ x1){
  __shared__ float A [67][132];    // [k][row] 35.4 KB
  __shared__ float Bw[67][68];     // [k][out] 18.2 KB
  __shared__ float sb[64];
  const int tid = threadIdx.x;
  if (tid < 64) sb[tid] = b0[tid];
  for (int idx = tid; idx < 64*67; idx += 256){
    int o = idx / 67, k = idx - o*67;
    Bw[k][o] = W0[idx];
  }
  const size_t rbase = (size_t)blockIdx.x * 128;
  {
    const int r  = tid & 127;
    const int hf = tid >> 7;           // half of the 64 points-channels
    const int R = (int)rbase + r;
    const int b_ = R >> 15, m_ = (R >> 5) & 1023;
    const int g_ = gidx[R];
    const float4* p4 = (const float4*)(points + (((size_t)(b_<<12) + g_) << 6) + hf*32);
#pragma unroll
    for (int j=0;j<8;j++){
      float4 v = p4[j];
      int c = 3 + hf*32 + j*4;
      A[c+0][r]=v.x; A[c+1][r]=v.y; A[c+2][r]=v.z; A[c+3][r]=v.w;
    }
    if (hf == 0){
      const float* pc = newxyz + ((size_t)(b_<<10) + m_)*3;
      const float* pp = xyz    + ((size_t)(b_<<12) + g_)*3;
      A[0][r] = pp[0]-pc[0];
      A[1][r] = pp[1]-pc[1];
      A[2][r] = pp[2]-pc[2];
    }
  }
  __syncthreads();
  const int tr = tid >> 4, tc = tid & 15;   // 8 rows x 4 cols per thread
  float acc[8][4];
#pragma unroll
  for (int i=0;i<8;i++)
#pragma unroll
    for (int j=0;j<4;j++) acc[i][j] = sb[tc*4+j];
#pragma unroll 4
  for (int k=0;k<67;k++){
    float4 a0 = *(const float4*)&A [k][tr*8];
    float4 a1 = *(const float4*)&A [k][tr*8+4];
    float4 w  = *(const float4*)&Bw[k][tc*4];
    float av[8] = {a0.x,a0.y,a0.z,a0.w,a1.x,a1.y,a1.z,a1.w};
#pragma unroll
    for (int i=0;i<8;i++){
      acc[i][0]=fmaf(av[i],w.x,acc[i][0]);
      acc[i][1]=fmaf(av[i],w.y,acc[i][1]);
      acc[i][2]=fmaf(av[i],w.z,acc[i][2]);
      acc[i][3]=fmaf(av[i],w.w,acc[i][3]);
    }
  }
#pragma unroll
  for (int i=0;i<8;i++){
    uint2 v;
    v.x = (uint)f2bf(acc[i][0]) | ((uint)f2bf(acc[i][1])<<16);
    v.y = (uint)f2bf(acc[i][2]) | ((uint)f2bf(acc[i][3])<<16);
    *(uint2*)(x1 + ((rbase + tr*8 + i) << 6) + tc*4) = v;
  }
}

// ---------- convg64 (conv1): BN+ReLU on read, 128x64 tile, K=64, acc 8x4 ----------
__global__ __launch_bounds__(256, 2) void convg64_kernel(const ushort* __restrict__ xin,
                                                         const float* __restrict__ Sv,
                                                         const float* __restrict__ SSv,
                                                         const float* __restrict__ gg,
                                                         const float* __restrict__ be,
                                                         const float* __restrict__ W,
                                                         const float* __restrict__ bias,
                                                         ushort* __restrict__ xout){
  __shared__ float A [64][132];    // [k][row] 33.8 KB
  __shared__ float Bw[64][68];     // [k][out] 17.4 KB
  __shared__ float sc[64], sh[64], sb[64];
  const int tid = threadIdx.x;
  if (tid < 64){
    int c = tid;
    float mean = Sv[c]*INV_CNT;
    float var  = fmaf(-mean, mean, SSv[c]*INV_CNT);
    float is   = rsqrtf(var + 1e-5f);
    float scv  = gg[c]*is;
    sc[c] = scv; sh[c] = fmaf(-mean, scv, be[c]);
    sb[c] = bias[c];
  }
  {
    const int o  = tid & 63;
    const int kq = tid >> 6;          // 0..3, 16 k each
    const float* wrow = W + (size_t)o*64 + kq*16;
#pragma unroll
    for (int q=0;q<4;q++){
      float4 wv = *(const float4*)(wrow + q*4);
      int k = kq*16 + q*4;
      Bw[k+0][o]=wv.x; Bw[k+1][o]=wv.y; Bw[k+2][o]=wv.z; Bw[k+3][o]=wv.w;
    }
  }
  __syncthreads();                    // sc/sh ready for A fill
  const size_t rbase = (size_t)blockIdx.x * 128;
  {
    const int r  = tid & 127;
    const int kh = tid >> 7;          // which 32-k half
    const uint4* src = (const uint4*)(xin + ((rbase + r) << 6) + kh*32);
#pragma unroll
    for (int g=0; g<4; g++){
      uint4 v = src[g];
      uint d[4] = {v.x,v.y,v.z,v.w};
#pragma unroll
      for (int q=0;q<4;q++){
        int k = kh*32 + g*8 + 2*q;
        float a0 = bf2f(d[q] & 0xffffu), a1 = bf2f(d[q] >> 16);
        A[k+0][r] = fmaxf(fmaf(a0, sc[k+0], sh[k+0]), 0.f);
        A[k+1][r] = fmaxf(fmaf(a1, sc[k+1], sh[k+1]), 0.f);
      }
    }
  }
  __syncthreads();
  const int tr = tid >> 4, tc = tid & 15;
  float acc[8][4];
#pragma unroll
  for (int i=0;i<8;i++)
#pragma unroll
    for (int j=0;j<4;j++) acc[i][j] = sb[tc*4+j];
#pragma unroll 4
  for (int k=0;k<64;k++){
    float4 a0 = *(const float4*)&A [k][tr*8];
    float4 a1 = *(const float4*)&A [k][tr*8+4];
    float4 w  = *(const float4*)&Bw[k][tc*4];
    float av[8] = {a0.x,a0.y,a0.z,a0.w,a1.x,a1.y,a1.z,a1.w};
#pragma unroll
    for (int i=0;i<8;i++){
      acc[i][0]=fmaf(av[i],w.x,acc[i][0]);
      acc[i][1]=fmaf(av[i],w.y,acc[i][1]);
      acc[i][2]=fmaf(av[i],w.z,acc[i][2]);
      acc[i][3]=fmaf(av[i],w.w,acc[i][3]);
    }
  }
#pragma unroll
  for (int i=0;i<8;i++){
    uint2 v;
    v.x = (uint)f2bf(acc[i][0]) | ((uint)f2bf(acc[i][1])<<16);
    v.y = (uint)f2bf(acc[i][2]) | ((uint)f2bf(acc[i][3])<<16);
    *(uint2*)(xout + ((rbase + tr*8 + i) << 6) + tc*4) = v;
  }
}

// ---------- convg128 (conv2): BN+ReLU on read, 128x128 tile, K=64, acc 8x8 ----------
__global__ __launch_bounds__(256, 2) void convg128_kernel(const ushort* __restrict__ xin,
                                                          const float* __restrict__ Sv,
                                                          const float* __restrict__ SSv,
                                                          const float* __restrict__ gg,
                                                          const float* __restrict__ be,
                                                          const float* __restrict__ W,
                                                          const float* __restrict__ bias,
                                                          ushort* __restrict__ xout){
  __shared__ float A [64][132];    // [k][row] 33.8 KB
  __shared__ float Bw[64][132];    // [k][out] 33.8 KB (128 used)
  __shared__ float sc[64], sh[64], sb[128];
  const int tid = threadIdx.x;
  if (tid < 64){
    int c = tid;
    float mean = Sv[c]*INV_CNT;
    float var  = fmaf(-mean, mean, SSv[c]*INV_CNT);
    float is   = rsqrtf(var + 1e-5f);
    float scv  = gg[c]*is;
    sc[c] = scv; sh[c] = fmaf(-mean, scv, be[c]);
  }
  if (tid < 128) sb[tid] = bias[tid];
  {
    const int o  = tid & 127;
    const int kh = tid >> 7;          // 0/1, 32 k each
    const float* wrow = W + (size_t)o*64 + kh*32;
#pragma unroll
    for (int q=0;q<8;q++){
      float4 wv = *(const float4*)(wrow + q*4);
      int k = kh*32 + q*4;
      Bw[k+0][o]=wv.x; Bw[k+1][o]=wv.y; Bw[k+2][o]=wv.z; Bw[k+3][o]=wv.w;
    }
  }
  __syncthreads();                    // sc/sh ready for A fill
  const size_t rbase = (size_t)blockIdx.x * 128;
  {
    const int r  = tid & 127;
    const int kh = tid >> 7;
    const uint4* src = (const uint4*)(xin + ((rbase + r) << 6) + kh*32);
#pragma unroll
    for (int g=0; g<4; g++){
      uint4 v = src[g];
      uint d[4] = {v.x,v.y,v.z,v.w};
#pragma unroll
      for (int q=0;q<4;q++){
        int k = kh*32 + g*8 + 2*q;
        float a0 = bf2f(d[q] & 0xffffu), a1 = bf2f(d[q] >> 16);
        A[k+0][r] = fmaxf(fmaf(a0, sc[k+0], sh[k+0]), 0.f);
        A[k+1][r] = fmaxf(fmaf(a1, sc[k+1], sh[k+1]), 0.f);
      }
    }
  }
  __syncthreads();
  const int tr = tid >> 4, tc = tid & 15;   // 8 rows x 8 cols per thread
  float acc[8][8];
#pragma unroll
  for (int i=0;i<8;i++)
#pragma unroll
    for (int j=0;j<8;j++) acc[i][j] = sb[tc*8+j];
#pragma unroll 2
  for (int k=0;k<64;k++){
    float4 a0 = *(const float4*)&A [k][tr*8];
    float4 a1 = *(const float4*)&A [k][tr*8+4];
    float4 w0 = *(const float4*)&Bw[k][tc*8];
    float4 w1 = *(const float4*)&Bw[k][tc*8+4];
    float av[8] = {a0.x,a0.y,a0.z,a0.w,a1.x,a1.y,a1.z,a1.w};
    float wv[8] = {w0.x,w0.y,w0.z,w0.w,w1.x,w1.y,w1.z,w1.w};
#pragma unroll
    for (int i=0;i<8;i++)
#pragma unroll
      for (int j=0;j<8;j++)
        acc[i][j] = fmaf(av[i], wv[j], acc[i][j]);
  }
#pragma unroll
  for (int i=0;i<8;i++){
    uint4 v;
    v.x = (uint)f2bf(acc[i][0]) | ((uint)f2bf(acc[i][1])<<16);
    v.y = (uint)f2bf(acc[i][2]) | ((uint)f2bf(acc[i][3])<<16);
    v.z = (uint)f2bf(acc[i][4]) | ((uint)f2bf(acc[i][5])<<16);
    v.w = (uint)f2bf(acc[i][6]) | ((uint)f2bf(acc[i][7])<<16);
    *(uint4*)(xout + ((rbase + tr*8 + i) << 7) + tc*8) = v;
  }
}

// ---------- stats: per-channel sum & sumsq, vectorized 8 ch/thread ----------
template<int C>
__global__ __launch_bounds__(256) void stats_kernel(const ushort* __restrict__ x,
                                                    float* __restrict__ S,
                                                    float* __restrict__ SS){
  constexpr int GRP = C/8;
  constexpr int RL  = 256/GRP;
  const int cg = threadIdx.x % GRP;
  const int rl = threadIdx.x / GRP;
  const int rows_per_block = NROWS / 1024;   // grid = 1024
  const int r0 = blockIdx.x * rows_per_block;
  float s[8], ss[8];
#pragma unroll
  for (int j=0;j<8;j++){ s[j]=0.f; ss[j]=0.f; }
  for (int r = r0 + rl; r < r0 + rows_per_block; r += RL){
    uint4 v = *(const uint4*)(x + (size_t)r*C + cg*8);
    uint d[4] = {v.x, v.y, v.z, v.w};
#pragma unroll
    for (int q=0;q<4;q++){
      float a0 = bf2f(d[q] & 0xffffu), a1 = bf2f(d[q] >> 16);
      s[2*q]   += a0; ss[2*q]   = fmaf(a0, a0, ss[2*q]);
      s[2*q+1] += a1; ss[2*q+1] = fmaf(a1, a1, ss[2*q+1]);
    }
  }
  __shared__ float ls[256][8], lss[256][8];
#pragma unroll
  for (int j=0;j<8;j++){ ls[threadIdx.x][j]=s[j]; lss[threadIdx.x][j]=ss[j]; }
  __syncthreads();
  if (threadIdx.x < C){
    const int grp = threadIdx.x >> 3, j = threadIdx.x & 7;
    float a = 0.f, q2 = 0.f;
#pragma unroll
    for (int q = 0; q < RL; q++){ a += ls[q*GRP + grp][j]; q2 += lss[q*GRP + grp][j]; }
    atomicAdd(&S[threadIdx.x], a); atomicAdd(&SS[threadIdx.x], q2);
  }
}

// ---------- BN2+ReLU + maxpool over K ----------
__global__ __launch_bounds__(256) void maxpool_kernel(const ushort* __restrict__ x3,
                                                      const float* __restrict__ S2,
                                                      const float* __restrict__ SS2,
                                                      const float* __restrict__ g2,
                                                      const float* __restrict__ be2,
                                                      float* __restrict__ outp){
  const int lane = threadIdx.x & 63, wv = threadIdx.x >> 6;
  const int bm = blockIdx.x*4 + wv;           // 16384 (b,m) groups
  const int c0 = lane*2, c1 = c0+1;
  float mean0 = S2[c0]*INV_CNT;
  float var0  = fmaf(-mean0, mean0, SS2[c0]*INV_CNT);
  float s0 = g2[c0]*rsqrtf(var0+1e-5f);
  float h0 = fmaf(-mean0, s0, be2[c0]);
  float mean1 = S2[c1]*INV_CNT;
  float var1  = fmaf(-mean1, mean1, SS2[c1]*INV_CNT);
  float s1 = g2[c1]*rsqrtf(var1+1e-5f);
  float h1 = fmaf(-mean1, s1, be2[c1]);
  const uint* rb = (const uint*)(x3 + (size_t)bm*K_SMP*128);
  float mx0 = 0.f, mx1 = 0.f;                 // relu floor
#pragma unroll
  for (int k=0;k<K_SMP;k++){
    uint v = rb[k*64 + lane];
    float a0 = bf2f(v & 0xffffu), a1 = bf2f(v >> 16);
    mx0 = fmaxf(mx0, fmaxf(fmaf(a0, s0, h0), 0.f));
    mx1 = fmaxf(mx1, fmaxf(fmaf(a1, s1, h1), 0.f));
  }
  float2* o2 = (float2*)(outp + (size_t)bm*128);
  o2[lane] = make_float2(mx0, mx1);
}

// ---------- launch ----------
extern "C" void kernel_launch(void* const* d_in, const int* in_sizes, int n_in,
                              void* d_out, int out_size, void* d_ws, size_t ws_size,
                              hipStream_t stream){
  const float* xyz    = (const float*)d_in[0];
  const float* points = (const float*)d_in[1];
  const float* w0  = (const float*)d_in[2];
  const float* b0  = (const float*)d_in[3];
  const float* g0  = (const float*)d_in[4];
  const float* be0 = (const float*)d_in[5];
  const float* w1  = (const float*)d_in[6];
  const float* b1  = (const float*)d_in[7];
  const float* g1  = (const float*)d_in[8];
  const float* be1 = (const float*)d_in[9];
  const float* w2  = (const float*)d_in[10];
  const float* b2  = (const float*)d_in[11];
  const float* g2  = (const float*)d_in[12];
  const float* be2 = (const float*)d_in[13];

  float* out      = (float*)d_out;
  float* newxyz   = out;                        // [16,1024,3]
  float* outp     = out + (size_t)B_SZ*M_PTS*3; // [16,1024,128]

  char* ws = (char*)d_ws;
  int*   gidx  = (int*)ws;
  float* stats = (float*)(ws + (2u<<20));
  float* S0 = stats,      *SS0 = stats+64;
  float* S1 = stats+128,  *SS1 = stats+192;
  float* S2 = stats+256,  *SS2 = stats+384;
  ushort* x1 = (ushort*)(ws + (4u<<20));
  ushort* x3 = (ushort*)(ws + (4u<<20));
  ushort* x2 = (ushort*)(ws + (4u<<20) + 134217728u);

  hipMemsetAsync(stats, 0, 512*sizeof(float), stream);
  fps_kernel  <<<B_SZ, 512, 0, stream>>>(xyz, newxyz);
  ballq_kernel<<<1024, 256, 0, stream>>>(xyz, newxyz, gidx);
  conv0_kernel<<<NROWS/128, 256, 0, stream>>>(xyz, points, newxyz, gidx, w0, b0, x1);
  stats_kernel<64><<<1024, 256, 0, stream>>>(x1, S0, SS0);
  convg64_kernel<<<NROWS/128, 256, 0, stream>>>(x1, S0, SS0, g0, be0, w1, b1, x2);
  stats_kernel<64><<<1024, 256, 0, stream>>>(x2, S1, SS1);
  convg128_kernel<<<NROWS/128, 256, 0, stream>>>(x2, S1, SS1, g1, be1, w2, b2, x3);
  stats_kernel<128><<<1024, 256, 0, stream>>>(x3, S2, SS2);
  maxpool_kernel<<<NROWS/128, 256, 0, stream>>>(x3, S2, SS2, g2, be2, outp);
}